// Round 1
// baseline (3533.364 us; speedup 1.0000x reference)
//
#include <hip/hip_runtime.h>
#include <math.h>

// GCN 2-layer forward, MI355X. Round 1: fp32 everywhere, atomic scatter.
// Pipeline: degrees -> norms -> GEMM1(x*ns @ W1) -> scatter-agg(128) ->
// epilogue1 (nd*agg+b1, relu, jax-threefry dropout, *ns fold) -> GEMM2 ->
// scatter-agg(47) into d_out -> in-place log_softmax.

#define NF0 256
#define NF1 128
#define NC  47

// ---------------- threefry2x32 (JAX partitionable path) ----------------
__device__ __forceinline__ unsigned rotl_(unsigned x, int n) {
  return (x << n) | (x >> (32 - n));
}

__device__ __forceinline__ void threefry2x32_(unsigned x0, unsigned x1,
                                              unsigned& o0, unsigned& o1) {
  const unsigned k0 = 0u, k1 = 42u;              // jax.random.key(42) -> (hi,lo)=(0,42)
  const unsigned k2 = k0 ^ k1 ^ 0x1BD11BDAu;
  x0 += k0; x1 += k1;
  x0+=x1; x1=rotl_(x1,13); x1^=x0;
  x0+=x1; x1=rotl_(x1,15); x1^=x0;
  x0+=x1; x1=rotl_(x1,26); x1^=x0;
  x0+=x1; x1=rotl_(x1, 6); x1^=x0;
  x0+=k1; x1+=k2+1u;
  x0+=x1; x1=rotl_(x1,17); x1^=x0;
  x0+=x1; x1=rotl_(x1,29); x1^=x0;
  x0+=x1; x1=rotl_(x1,16); x1^=x0;
  x0+=x1; x1=rotl_(x1,24); x1^=x0;
  x0+=k2; x1+=k0+2u;
  x0+=x1; x1=rotl_(x1,13); x1^=x0;
  x0+=x1; x1=rotl_(x1,15); x1^=x0;
  x0+=x1; x1=rotl_(x1,26); x1^=x0;
  x0+=x1; x1=rotl_(x1, 6); x1^=x0;
  x0+=k0; x1+=k1+3u;
  x0+=x1; x1=rotl_(x1,17); x1^=x0;
  x0+=x1; x1=rotl_(x1,29); x1^=x0;
  x0+=x1; x1=rotl_(x1,16); x1^=x0;
  x0+=x1; x1=rotl_(x1,24); x1^=x0;
  x0+=k1; x1+=k2+4u;
  x0+=x1; x1=rotl_(x1,13); x1^=x0;
  x0+=x1; x1=rotl_(x1,15); x1^=x0;
  x0+=x1; x1=rotl_(x1,26); x1^=x0;
  x0+=x1; x1=rotl_(x1, 6); x1^=x0;
  x0+=k2; x1+=k0+5u;
  o0 = x0; o1 = x1;
}

// keep-multiplier for flat element j of the (N,128) dropout mask:
// partitionable threefry: ctr64 = j -> (hi,lo)=(0,j); bits = o0 ^ o1
__device__ __forceinline__ float dropout_mul(int j) {
  unsigned o0, o1;
  threefry2x32_(0u, (unsigned)j, o0, o1);
  unsigned bits = o0 ^ o1;
  float u = __uint_as_float((bits >> 9) | 0x3f800000u) - 1.0f;
  return (u < 0.8f) ? 1.25f : 0.0f;   // h/0.8 == h*1.25 to within 1 ulp
}

// ---------------- degrees & norms ----------------
__global__ __launch_bounds__(256) void k_degree(const int* __restrict__ ei, int E,
                                                unsigned* __restrict__ deg_s,
                                                unsigned* __restrict__ deg_d) {
  int e = blockIdx.x * 256 + threadIdx.x;
  if (e < E) {
    atomicAdd(&deg_s[ei[e]], 1u);
    atomicAdd(&deg_d[ei[E + e]], 1u);
  }
}

__global__ __launch_bounds__(256) void k_norm(float* __restrict__ buf, int n2) {
  int i = blockIdx.x * 256 + threadIdx.x;
  if (i < n2) {
    unsigned d = ((const unsigned*)buf)[i];
    float df = (float)(d < 1u ? 1u : d);
    buf[i] = 1.0f / sqrtf(df);
  }
}

// ---------------- GEMM1: h1[m,f] = norm_src[m] * sum_k x[m,k] W1[k,f] ----------------
// block: 256 thr, 64 nodes x 128 feats; thread tile 8 nodes x 4 feats.
__global__ __launch_bounds__(256) void k_gemm1(const float* __restrict__ x,
                                               const float* __restrict__ W1,
                                               const float* __restrict__ norm_src,
                                               float* __restrict__ h1, int N) {
  __shared__ float As[64][36];    // pad 32->36: conflict-free f4 stores
  __shared__ float Bs[32][128];
  const int m0 = blockIdx.x * 64;
  const int t = threadIdx.x;
  const int tx = t & 31, ty = t >> 5;
  float acc[8][4] = {{0.f}};

  for (int k0 = 0; k0 < NF0; k0 += 32) {
    #pragma unroll
    for (int l = t; l < 64 * 8; l += 256) {         // A: 512 float4
      int r = l >> 3, c = (l & 7) << 2;
      int gm = m0 + r;
      float4 v = make_float4(0.f, 0.f, 0.f, 0.f);
      if (gm < N) v = *(const float4*)(x + (size_t)gm * NF0 + k0 + c);
      *(float4*)&As[r][c] = v;
    }
    #pragma unroll
    for (int l = t; l < 32 * 32; l += 256) {        // B: 1024 float4
      int r = l >> 5, c = (l & 31) << 2;
      *(float4*)&Bs[r][c] = *(const float4*)(W1 + (size_t)(k0 + r) * NF1 + c);
    }
    __syncthreads();
    #pragma unroll
    for (int k = 0; k < 32; k++) {
      float4 b = *(float4*)&Bs[k][tx << 2];
      float a[8];
      #pragma unroll
      for (int i = 0; i < 8; i++) a[i] = As[ty * 8 + i][k];
      #pragma unroll
      for (int i = 0; i < 8; i++) {
        acc[i][0] += a[i] * b.x; acc[i][1] += a[i] * b.y;
        acc[i][2] += a[i] * b.z; acc[i][3] += a[i] * b.w;
      }
    }
    __syncthreads();
  }
  #pragma unroll
  for (int i = 0; i < 8; i++) {
    int gm = m0 + ty * 8 + i;
    if (gm < N) {
      float ns = norm_src[gm];
      float4 o = make_float4(acc[i][0]*ns, acc[i][1]*ns, acc[i][2]*ns, acc[i][3]*ns);
      *(float4*)(h1 + (size_t)gm * NF1 + (tx << 2)) = o;
    }
  }
}

// ---------------- scatter layer1: agg[dst] += h1[src], 128 feats ----------------
__global__ __launch_bounds__(256) void k_scatter1(const int* __restrict__ ei, int E,
                                                  const float* __restrict__ h1,
                                                  float* __restrict__ agg) {
  __shared__ int ss[8], dd[8];
  int e0 = blockIdx.x * 8;
  if (threadIdx.x < 8) {
    int e = e0 + threadIdx.x;
    ss[threadIdx.x] = (e < E) ? ei[e] : -1;
    dd[threadIdx.x] = (e < E) ? ei[E + e] : -1;
  }
  __syncthreads();
  int sub = threadIdx.x >> 5, lane = threadIdx.x & 31;
  if (e0 + sub >= E) return;
  int s = ss[sub], d = dd[sub];
  float4 v = *(const float4*)(h1 + (size_t)s * NF1 + (lane << 2));
  float* o = agg + (size_t)d * NF1 + (lane << 2);
  atomicAdd(o + 0, v.x); atomicAdd(o + 1, v.y);
  atomicAdd(o + 2, v.z); atomicAdd(o + 3, v.w);
}

// ---------------- epilogue1: h2 = dropout(relu(agg*nd + b1)) * ns ----------------
__global__ __launch_bounds__(256) void k_epilogue1(const float* __restrict__ agg,
                                                   const float* __restrict__ norm_dst,
                                                   const float* __restrict__ norm_src,
                                                   const float* __restrict__ b1,
                                                   float* __restrict__ h2, int total) {
  int j = blockIdx.x * 256 + threadIdx.x;
  if (j >= total) return;
  int node = j >> 7, f = j & 127;
  float v = fmaxf(agg[j] * norm_dst[node] + b1[f], 0.f);
  h2[j] = v * dropout_mul(j) * norm_src[node];
}

// ---------------- GEMM2: g[m,f] = sum_k h2[m,k] W2[k,f]  (f<47) ----------------
// block: 256 thr, 64 nodes x 48 feats (col 47 zero-padded); thread tile 4x3.
__global__ __launch_bounds__(256) void k_gemm2(const float* __restrict__ h2,
                                               const float* __restrict__ W2,
                                               float* __restrict__ g, int N) {
  __shared__ float hs[64][132];
  __shared__ float w2t[48][132];   // transposed, row f holds k=0..127
  const int m0 = blockIdx.x * 64;
  const int t = threadIdx.x;
  #pragma unroll
  for (int l = t; l < 64 * 32; l += 256) {
    int r = l >> 5, c = (l & 31) << 2;
    float4 v = make_float4(0.f, 0.f, 0.f, 0.f);
    int gm = m0 + r;
    if (gm < N) v = *(const float4*)(h2 + (size_t)gm * NF1 + c);
    *(float4*)&hs[r][c] = v;
  }
  for (int l = t; l < 48 * 128; l += 256) {
    int k = l / 48, f = l - k * 48;      // consecutive threads -> consecutive f (coalesced)
    w2t[f][k] = (f < NC) ? W2[(size_t)k * NC + f] : 0.f;
  }
  __syncthreads();
  const int fg = t & 15, mg = t >> 4;
  const int f0 = fg * 3, mt = mg * 4;
  float acc[4][3] = {{0.f}};
  for (int k = 0; k < NF1; k += 4) {
    float4 a[4], b[3];
    #pragma unroll
    for (int i = 0; i < 4; i++) a[i] = *(float4*)&hs[mt + i][k];
    #pragma unroll
    for (int j = 0; j < 3; j++) b[j] = *(float4*)&w2t[f0 + j][k];
    #pragma unroll
    for (int i = 0; i < 4; i++)
      #pragma unroll
      for (int j = 0; j < 3; j++)
        acc[i][j] += a[i].x*b[j].x + a[i].y*b[j].y + a[i].z*b[j].z + a[i].w*b[j].w;
  }
  #pragma unroll
  for (int i = 0; i < 4; i++) {
    int gm = m0 + mt + i;
    if (gm < N) {
      #pragma unroll
      for (int j = 0; j < 3; j++) {
        int f = f0 + j;
        if (f < NC) g[(size_t)gm * NC + f] = acc[i][j];
      }
    }
  }
}

// ---------------- scatter layer2: out[dst] += g[src], 47 feats ----------------
__global__ __launch_bounds__(256) void k_scatter2(const int* __restrict__ ei, int E,
                                                  const float* __restrict__ g,
                                                  float* __restrict__ out) {
  int id = blockIdx.x * 256 + threadIdx.x;    // over E*48
  int e = id / 48;
  int f = id - e * 48;
  if (e >= E || f >= NC) return;
  int s = ei[e], d = ei[E + e];
  atomicAdd(out + (size_t)d * NC + f, g[(size_t)s * NC + f]);
}

// ---------------- final: out = log_softmax(out*nd + b2), one wave/node ----------------
__global__ __launch_bounds__(256) void k_final(float* __restrict__ out,
                                               const float* __restrict__ norm_dst,
                                               const float* __restrict__ b2, int N) {
  int wid = (blockIdx.x * 256 + threadIdx.x) >> 6;
  int lane = threadIdx.x & 63;
  if (wid >= N) return;
  float nd = norm_dst[wid];
  float vr = 0.f, v = -INFINITY;
  if (lane < NC) {
    vr = out[(size_t)wid * NC + lane] * nd + b2[lane];
    v = vr;
  }
  #pragma unroll
  for (int o = 32; o; o >>= 1) v = fmaxf(v, __shfl_xor(v, o));
  float ex = (lane < NC) ? expf(vr - v) : 0.f;
  float s = ex;
  #pragma unroll
  for (int o = 32; o; o >>= 1) s += __shfl_xor(s, o);
  float ls = logf(s);
  if (lane < NC) out[(size_t)wid * NC + lane] = vr - v - ls;
}

extern "C" void kernel_launch(void* const* d_in, const int* in_sizes, int n_in,
                              void* d_out, int out_size, void* d_ws, size_t ws_size,
                              hipStream_t stream) {
  const float* x  = (const float*)d_in[0];
  const int*   ei = (const int*)d_in[1];       // int64 in ref -> harness delivers int32
  const float* W1 = (const float*)d_in[2];
  const float* b1 = (const float*)d_in[3];
  const float* W2 = (const float*)d_in[4];
  const float* b2 = (const float*)d_in[5];
  float* out = (float*)d_out;

  const int N = in_sizes[0] / NF0;             // 100000
  const int E = in_sizes[1] / 2;               // 1600000

  float* ws = (float*)d_ws;
  float* norm_src = ws;                         // N (degree scratch as uint, then norm)
  float* norm_dst = ws + N;                     // N
  float* h1       = ws + 2 * (size_t)N;         // N*128 (later reused as h2)
  // agg buffer (N*128 floats), also reused for g (N*47):
  size_t needA = ((size_t)2 * N + 2 * (size_t)N * NF1) * sizeof(float);
  float* aggbuf = (ws_size >= needA)
                      ? (h1 + (size_t)N * NF1)  // layout A: all in ws
                      : (float*)d_in[0];        // layout B: reuse x (restored each call)

  hipMemsetAsync(norm_src, 0, (size_t)2 * N * sizeof(float), stream);
  hipMemsetAsync(d_out, 0, (size_t)N * NC * sizeof(float), stream);

  k_degree<<<(E + 255) / 256, 256, 0, stream>>>(ei, E, (unsigned*)norm_src,
                                                (unsigned*)norm_dst);
  k_norm<<<(2 * N + 255) / 256, 256, 0, stream>>>(norm_src, 2 * N);
  k_gemm1<<<(N + 63) / 64, 256, 0, stream>>>(x, W1, norm_src, h1, N);
  // agg memset AFTER gemm1 (layout B aliases x):
  hipMemsetAsync(aggbuf, 0, (size_t)N * NF1 * sizeof(float), stream);
  k_scatter1<<<(E + 7) / 8, 256, 0, stream>>>(ei, E, h1, aggbuf);
  k_epilogue1<<<(N * NF1 + 255) / 256, 256, 0, stream>>>(aggbuf, norm_dst, norm_src,
                                                         b1, h1, N * NF1);
  k_gemm2<<<(N + 63) / 64, 256, 0, stream>>>(h1, W2, aggbuf, N);
  k_scatter2<<<((size_t)E * 48 + 255) / 256, 256, 0, stream>>>(ei, E, aggbuf, out);
  k_final<<<((size_t)N * 64 + 255) / 256, 256, 0, stream>>>(out, norm_dst, b2, N);
}

// Round 2
// 756.153 us; speedup vs baseline: 4.6728x; 4.6728x over previous
//
#include <hip/hip_runtime.h>
#include <math.h>

// GCN 2-layer forward, MI355X. Round 2: CSR gather instead of atomic scatter.
// Pipeline: degrees -> scan(deg_dst)->CSR offsets -> norms -> fill CSR ->
// GEMM1 -> gather1 (+norm/bias/relu/dropout/ns fused) -> GEMM2 (48-padded) ->
// gather2 (+norm/bias/log_softmax fused) -> d_out.

#define NF0 256
#define NF1 128
#define NC  47

// ---------------- threefry2x32 (JAX partitionable path) ----------------
__device__ __forceinline__ unsigned rotl_(unsigned x, int n) {
  return (x << n) | (x >> (32 - n));
}

__device__ __forceinline__ void threefry2x32_(unsigned x0, unsigned x1,
                                              unsigned& o0, unsigned& o1) {
  const unsigned k0 = 0u, k1 = 42u;              // jax.random.key(42)
  const unsigned k2 = k0 ^ k1 ^ 0x1BD11BDAu;
  x0 += k0; x1 += k1;
  x0+=x1; x1=rotl_(x1,13); x1^=x0;
  x0+=x1; x1=rotl_(x1,15); x1^=x0;
  x0+=x1; x1=rotl_(x1,26); x1^=x0;
  x0+=x1; x1=rotl_(x1, 6); x1^=x0;
  x0+=k1; x1+=k2+1u;
  x0+=x1; x1=rotl_(x1,17); x1^=x0;
  x0+=x1; x1=rotl_(x1,29); x1^=x0;
  x0+=x1; x1=rotl_(x1,16); x1^=x0;
  x0+=x1; x1=rotl_(x1,24); x1^=x0;
  x0+=k2; x1+=k0+2u;
  x0+=x1; x1=rotl_(x1,13); x1^=x0;
  x0+=x1; x1=rotl_(x1,15); x1^=x0;
  x0+=x1; x1=rotl_(x1,26); x1^=x0;
  x0+=x1; x1=rotl_(x1, 6); x1^=x0;
  x0+=k0; x1+=k1+3u;
  x0+=x1; x1=rotl_(x1,17); x1^=x0;
  x0+=x1; x1=rotl_(x1,29); x1^=x0;
  x0+=x1; x1=rotl_(x1,16); x1^=x0;
  x0+=x1; x1=rotl_(x1,24); x1^=x0;
  x0+=k1; x1+=k2+4u;
  x0+=x1; x1=rotl_(x1,13); x1^=x0;
  x0+=x1; x1=rotl_(x1,15); x1^=x0;
  x0+=x1; x1=rotl_(x1,26); x1^=x0;
  x0+=x1; x1=rotl_(x1, 6); x1^=x0;
  x0+=k2; x1+=k0+5u;
  o0 = x0; o1 = x1;
}

__device__ __forceinline__ float dropout_mul(int j) {
  unsigned o0, o1;
  threefry2x32_(0u, (unsigned)j, o0, o1);
  unsigned bits = o0 ^ o1;
  float u = __uint_as_float((bits >> 9) | 0x3f800000u) - 1.0f;
  return (u < 0.8f) ? 1.25f : 0.0f;
}

// ---------------- degrees ----------------
__global__ __launch_bounds__(256) void k_degree(const int* __restrict__ ei, int E,
                                                unsigned* __restrict__ deg_s,
                                                unsigned* __restrict__ deg_d) {
  int e = blockIdx.x * 256 + threadIdx.x;
  if (e < E) {
    atomicAdd(&deg_s[ei[e]], 1u);
    atomicAdd(&deg_d[ei[E + e]], 1u);
  }
}

__global__ __launch_bounds__(256) void k_norm(float* __restrict__ buf, int n2) {
  int i = blockIdx.x * 256 + threadIdx.x;
  if (i < n2) {
    unsigned d = ((const unsigned*)buf)[i];
    float df = (float)(d < 1u ? 1u : d);
    buf[i] = 1.0f / sqrtf(df);
  }
}

// ---------------- exclusive scan of deg_dst -> off ----------------
#define SCB 256
__global__ __launch_bounds__(SCB) void k_scan1(const unsigned* __restrict__ deg,
                                               unsigned* __restrict__ off,
                                               unsigned* __restrict__ bsum, int n) {
  __shared__ unsigned s[SCB];
  int t = threadIdx.x;
  int i = blockIdx.x * SCB + t;
  unsigned v = (i < n) ? deg[i] : 0u;
  s[t] = v;
  __syncthreads();
  #pragma unroll
  for (int o = 1; o < SCB; o <<= 1) {
    unsigned u = (t >= o) ? s[t - o] : 0u;
    __syncthreads();
    s[t] += u;
    __syncthreads();
  }
  if (i < n) off[i] = s[t] - v;              // exclusive within block
  if (t == SCB - 1) bsum[blockIdx.x] = s[t]; // block total
}

__global__ __launch_bounds__(512) void k_scan2(unsigned* __restrict__ bsum, int nb) {
  __shared__ unsigned s[512];
  int t = threadIdx.x;
  unsigned v = (t < nb) ? bsum[t] : 0u;
  s[t] = v;
  __syncthreads();
  #pragma unroll
  for (int o = 1; o < 512; o <<= 1) {
    unsigned u = (t >= o) ? s[t - o] : 0u;
    __syncthreads();
    s[t] += u;
    __syncthreads();
  }
  if (t < nb) bsum[t] = s[t] - v;            // exclusive block offsets
}

__global__ __launch_bounds__(SCB) void k_scan3(unsigned* __restrict__ off,
                                               const unsigned* __restrict__ bsum,
                                               int n, int E) {
  int i = blockIdx.x * SCB + threadIdx.x;
  if (i < n) off[i] += bsum[blockIdx.x];
  if (i == 0) off[n] = (unsigned)E;
}

// ---------------- CSR fill: bucket src by dst ----------------
__global__ __launch_bounds__(256) void k_fill(const int* __restrict__ ei, int E,
                                              const unsigned* __restrict__ off,
                                              unsigned* __restrict__ cursor,
                                              int* __restrict__ csr) {
  int e = blockIdx.x * 256 + threadIdx.x;
  if (e < E) {
    int s = ei[e], d = ei[E + e];
    unsigned p = atomicAdd(&cursor[d], 1u);
    csr[off[d] + p] = s;
  }
}

// ---------------- GEMM1: h1[m,f] = norm_src[m] * sum_k x[m,k] W1[k,f] ----------------
__global__ __launch_bounds__(256) void k_gemm1(const float* __restrict__ x,
                                               const float* __restrict__ W1,
                                               const float* __restrict__ norm_src,
                                               float* __restrict__ h1, int N) {
  __shared__ float As[64][36];
  __shared__ float Bs[32][128];
  const int m0 = blockIdx.x * 64;
  const int t = threadIdx.x;
  const int tx = t & 31, ty = t >> 5;
  float acc[8][4] = {{0.f}};

  for (int k0 = 0; k0 < NF0; k0 += 32) {
    #pragma unroll
    for (int l = t; l < 64 * 8; l += 256) {
      int r = l >> 3, c = (l & 7) << 2;
      int gm = m0 + r;
      float4 v = make_float4(0.f, 0.f, 0.f, 0.f);
      if (gm < N) v = *(const float4*)(x + (size_t)gm * NF0 + k0 + c);
      *(float4*)&As[r][c] = v;
    }
    #pragma unroll
    for (int l = t; l < 32 * 32; l += 256) {
      int r = l >> 5, c = (l & 31) << 2;
      *(float4*)&Bs[r][c] = *(const float4*)(W1 + (size_t)(k0 + r) * NF1 + c);
    }
    __syncthreads();
    #pragma unroll
    for (int k = 0; k < 32; k++) {
      float4 b = *(float4*)&Bs[k][tx << 2];
      float a[8];
      #pragma unroll
      for (int i = 0; i < 8; i++) a[i] = As[ty * 8 + i][k];
      #pragma unroll
      for (int i = 0; i < 8; i++) {
        acc[i][0] += a[i] * b.x; acc[i][1] += a[i] * b.y;
        acc[i][2] += a[i] * b.z; acc[i][3] += a[i] * b.w;
      }
    }
    __syncthreads();
  }
  #pragma unroll
  for (int i = 0; i < 8; i++) {
    int gm = m0 + ty * 8 + i;
    if (gm < N) {
      float ns = norm_src[gm];
      float4 o = make_float4(acc[i][0]*ns, acc[i][1]*ns, acc[i][2]*ns, acc[i][3]*ns);
      *(float4*)(h1 + (size_t)gm * NF1 + (tx << 2)) = o;
    }
  }
}

// ---------------- gather1: h2[n] = dropout(relu(nd*sum_{e in} h1[src] + b1)) * ns ----------------
// one wave per node; lane covers 2 feats (float2), row read = 512B coalesced.
__global__ __launch_bounds__(256) void k_gather1(const unsigned* __restrict__ off,
                                                 const int* __restrict__ csr,
                                                 const float* __restrict__ h1,
                                                 const float* __restrict__ norm_dst,
                                                 const float* __restrict__ norm_src,
                                                 const float* __restrict__ b1,
                                                 float* __restrict__ h2, int N) {
  int node = (blockIdx.x * 256 + threadIdx.x) >> 6;
  int lane = threadIdx.x & 63;
  if (node >= N) return;
  unsigned j = off[node], e1 = off[node + 1];
  int f = lane << 1;
  float ax = 0.f, ay = 0.f;
  for (; j + 2 <= e1; j += 2) {                 // unroll 2: independent loads
    int sa = csr[j], sb = csr[j + 1];
    float2 va = *(const float2*)(h1 + (size_t)sa * NF1 + f);
    float2 vb = *(const float2*)(h1 + (size_t)sb * NF1 + f);
    ax += va.x + vb.x; ay += va.y + vb.y;
  }
  if (j < e1) {
    float2 va = *(const float2*)(h1 + (size_t)csr[j] * NF1 + f);
    ax += va.x; ay += va.y;
  }
  float nd = norm_dst[node], ns = norm_src[node];
  float2 bb = *(const float2*)(b1 + f);
  float v0 = fmaxf(ax * nd + bb.x, 0.f);
  float v1 = fmaxf(ay * nd + bb.y, 0.f);
  int jf = node * NF1 + f;
  v0 *= dropout_mul(jf) * ns;
  v1 *= dropout_mul(jf + 1) * ns;
  *(float2*)(h2 + (size_t)node * NF1 + f) = make_float2(v0, v1);
}

// ---------------- GEMM2: g[m,f] = sum_k h2[m,k] W2[k,f], stride 48, col47=0 ----------------
__global__ __launch_bounds__(256) void k_gemm2(const float* __restrict__ h2,
                                               const float* __restrict__ W2,
                                               float* __restrict__ g, int N) {
  __shared__ float hs[64][132];
  __shared__ float w2t[48][132];
  const int m0 = blockIdx.x * 64;
  const int t = threadIdx.x;
  #pragma unroll
  for (int l = t; l < 64 * 32; l += 256) {
    int r = l >> 5, c = (l & 31) << 2;
    float4 v = make_float4(0.f, 0.f, 0.f, 0.f);
    int gm = m0 + r;
    if (gm < N) v = *(const float4*)(h2 + (size_t)gm * NF1 + c);
    *(float4*)&hs[r][c] = v;
  }
  for (int l = t; l < 48 * 128; l += 256) {
    int k = l / 48, f = l - k * 48;
    w2t[f][k] = (f < NC) ? W2[(size_t)k * NC + f] : 0.f;
  }
  __syncthreads();
  const int fg = t & 15, mg = t >> 4;
  const int f0 = fg * 3, mt = mg * 4;
  float acc[4][3] = {{0.f}};
  for (int k = 0; k < NF1; k += 4) {
    float4 a[4], b[3];
    #pragma unroll
    for (int i = 0; i < 4; i++) a[i] = *(float4*)&hs[mt + i][k];
    #pragma unroll
    for (int j = 0; j < 3; j++) b[j] = *(float4*)&w2t[f0 + j][k];
    #pragma unroll
    for (int i = 0; i < 4; i++)
      #pragma unroll
      for (int j = 0; j < 3; j++)
        acc[i][j] += a[i].x*b[j].x + a[i].y*b[j].y + a[i].z*b[j].z + a[i].w*b[j].w;
  }
  #pragma unroll
  for (int i = 0; i < 4; i++) {
    int gm = m0 + mt + i;
    if (gm < N) {
      #pragma unroll
      for (int j = 0; j < 3; j++)
        g[(size_t)gm * 48 + f0 + j] = acc[i][j];   // col 47 = 0 (padded w2t)
    }
  }
}

// ---------------- gather2 + bias + log_softmax -> out ----------------
__global__ __launch_bounds__(256) void k_gather2(const unsigned* __restrict__ off,
                                                 const int* __restrict__ csr,
                                                 const float* __restrict__ g,
                                                 const float* __restrict__ norm_dst,
                                                 const float* __restrict__ b2,
                                                 float* __restrict__ out, int N) {
  int node = (blockIdx.x * 256 + threadIdx.x) >> 6;
  int lane = threadIdx.x & 63;
  if (node >= N) return;
  unsigned j = off[node], e1 = off[node + 1];
  float acc = 0.f;
  for (; j + 2 <= e1; j += 2) {
    int sa = csr[j], sb = csr[j + 1];
    if (lane < 48) acc += g[(size_t)sa * 48 + lane] + g[(size_t)sb * 48 + lane];
  }
  if (j < e1 && lane < 48) acc += g[(size_t)csr[j] * 48 + lane];
  float nd = norm_dst[node];
  float vr = 0.f, m = -INFINITY;
  if (lane < NC) {
    vr = acc * nd + b2[lane];
    m = vr;
  }
  #pragma unroll
  for (int o = 32; o; o >>= 1) m = fmaxf(m, __shfl_xor(m, o));
  float ex = (lane < NC) ? expf(vr - m) : 0.f;
  #pragma unroll
  for (int o = 32; o; o >>= 1) ex += __shfl_xor(ex, o);
  float ls = logf(ex);
  if (lane < NC) out[(size_t)node * NC + lane] = vr - m - ls;
}

extern "C" void kernel_launch(void* const* d_in, const int* in_sizes, int n_in,
                              void* d_out, int out_size, void* d_ws, size_t ws_size,
                              hipStream_t stream) {
  const float* x  = (const float*)d_in[0];
  const int*   ei = (const int*)d_in[1];
  const float* W1 = (const float*)d_in[2];
  const float* b1 = (const float*)d_in[3];
  const float* W2 = (const float*)d_in[4];
  const float* b2 = (const float*)d_in[5];
  float* out = (float*)d_out;

  const int N = in_sizes[0] / NF0;   // 100000
  const int E = in_sizes[1] / 2;     // 1600000
  const int nb = (N + SCB - 1) / SCB;

  // ws bump allocator (element offsets, 16B-aligned chunks)
  unsigned* ws = (unsigned*)d_ws;
  size_t o = 0;
  auto alloc = [&](size_t elems) { size_t p = o; o += (elems + 3) & ~(size_t)3; return p; };
  unsigned* deg_src = ws + alloc(N);        // -> norm_src (float, in place)
  unsigned* deg_dst = ws + alloc(N);        // -> norm_dst
  unsigned* cursor  = ws + alloc(N);
  unsigned* off     = ws + alloc(N + 1);
  unsigned* bsum    = ws + alloc(1024);
  int*      csr     = (int*)(ws + alloc(E));
  float*    h1      = (float*)(ws + alloc((size_t)N * NF1));  // reused as g (stride 48)
  size_t need_h2 = (o + (size_t)N * NF1) * 4;
  float* h2 = (ws_size >= need_h2) ? (float*)(ws + alloc((size_t)N * NF1))
                                   : (float*)d_in[0];  // overlay x (dead after gemm1;
                                                       // harness restores inputs each call)
  float* g = h1;  // h1 dead after gather1

  // zero deg_src, deg_dst, cursor (contiguous 3N)
  hipMemsetAsync(deg_src, 0, (size_t)3 * N * sizeof(unsigned), stream);

  k_degree<<<(E + 255) / 256, 256, 0, stream>>>(ei, E, deg_src, deg_dst);
  k_scan1<<<nb, SCB, 0, stream>>>(deg_dst, off, bsum, N);
  k_scan2<<<1, 512, 0, stream>>>(bsum, nb);
  k_scan3<<<nb, SCB, 0, stream>>>(off, bsum, N, E);
  k_norm<<<(2 * N + 255) / 256, 256, 0, stream>>>((float*)deg_src, 2 * N);
  k_fill<<<(E + 255) / 256, 256, 0, stream>>>(ei, E, off, cursor, csr);
  k_gemm1<<<(N + 63) / 64, 256, 0, stream>>>(x, W1, (const float*)deg_src, h1, N);
  k_gather1<<<((size_t)N * 64 + 255) / 256, 256, 0, stream>>>(
      off, csr, h1, (const float*)deg_dst, (const float*)deg_src, b1, h2, N);
  k_gemm2<<<(N + 63) / 64, 256, 0, stream>>>(h2, W2, g, N);
  k_gather2<<<((size_t)N * 64 + 255) / 256, 256, 0, stream>>>(
      off, csr, g, (const float*)deg_dst, b2, out, N);
}

// Round 4
// 635.354 us; speedup vs baseline: 5.5613x; 1.1901x over previous
//
#include <hip/hip_runtime.h>
#include <math.h>

// GCN 2-layer forward, MI355X. Round 4: r3 pipeline with the TBAA-UB fixed.
// k_gemm1 staging now packs bf16 pairs into unsigned words (no ushort->uint4
// store/load pun); LDS tiles typed unsigned; W1t stored as packed uint pairs.

#define NF0 256
#define NF1 128
#define NC  47

typedef __attribute__((ext_vector_type(8))) short bfrag;   // 8 bf16 (4 VGPRs)
typedef __attribute__((ext_vector_type(4))) float f32x4;

__device__ __forceinline__ unsigned short f2bf(float f) {   // RNE
  unsigned u = __float_as_uint(f);
  return (unsigned short)((u + 0x7fffu + ((u >> 16) & 1u)) >> 16);
}
__device__ __forceinline__ unsigned pack2bf(float a, float b) {
  return (unsigned)f2bf(a) | ((unsigned)f2bf(b) << 16);
}
__device__ __forceinline__ float bf2f(unsigned short b) {
  return __uint_as_float((unsigned)b << 16);
}
__device__ __forceinline__ float bflo(unsigned v) { return __uint_as_float(v << 16); }
__device__ __forceinline__ float bfhi(unsigned v) { return __uint_as_float(v & 0xffff0000u); }

// ---------------- threefry2x32 (JAX partitionable path; verified r1/r2) ------------
__device__ __forceinline__ unsigned rotl_(unsigned x, int n) {
  return (x << n) | (x >> (32 - n));
}
__device__ __forceinline__ void threefry2x32_(unsigned x0, unsigned x1,
                                              unsigned& o0, unsigned& o1) {
  const unsigned k0 = 0u, k1 = 42u;
  const unsigned k2 = k0 ^ k1 ^ 0x1BD11BDAu;
  x0 += k0; x1 += k1;
  x0+=x1; x1=rotl_(x1,13); x1^=x0;
  x0+=x1; x1=rotl_(x1,15); x1^=x0;
  x0+=x1; x1=rotl_(x1,26); x1^=x0;
  x0+=x1; x1=rotl_(x1, 6); x1^=x0;
  x0+=k1; x1+=k2+1u;
  x0+=x1; x1=rotl_(x1,17); x1^=x0;
  x0+=x1; x1=rotl_(x1,29); x1^=x0;
  x0+=x1; x1=rotl_(x1,16); x1^=x0;
  x0+=x1; x1=rotl_(x1,24); x1^=x0;
  x0+=k2; x1+=k0+2u;
  x0+=x1; x1=rotl_(x1,13); x1^=x0;
  x0+=x1; x1=rotl_(x1,15); x1^=x0;
  x0+=x1; x1=rotl_(x1,26); x1^=x0;
  x0+=x1; x1=rotl_(x1, 6); x1^=x0;
  x0+=k0; x1+=k1+3u;
  x0+=x1; x1=rotl_(x1,17); x1^=x0;
  x0+=x1; x1=rotl_(x1,29); x1^=x0;
  x0+=x1; x1=rotl_(x1,16); x1^=x0;
  x0+=x1; x1=rotl_(x1,24); x1^=x0;
  x0+=k1; x1+=k2+4u;
  x0+=x1; x1=rotl_(x1,13); x1^=x0;
  x0+=x1; x1=rotl_(x1,15); x1^=x0;
  x0+=x1; x1=rotl_(x1,26); x1^=x0;
  x0+=x1; x1=rotl_(x1, 6); x1^=x0;
  x0+=k2; x1+=k0+5u;
  o0 = x0; o1 = x1;
}
__device__ __forceinline__ float dropout_mul(int j) {
  unsigned o0, o1;
  threefry2x32_(0u, (unsigned)j, o0, o1);
  unsigned bits = o0 ^ o1;
  float u = __uint_as_float((bits >> 9) | 0x3f800000u) - 1.0f;
  return (u < 0.8f) ? 1.25f : 0.0f;
}

// ---------------- degrees & norms ----------------
__global__ __launch_bounds__(256) void k_degree(const int* __restrict__ ei, int E,
                                                unsigned* __restrict__ deg_s,
                                                unsigned* __restrict__ deg_d) {
  int e = blockIdx.x * 256 + threadIdx.x;
  if (e < E) {
    atomicAdd(&deg_s[ei[e]], 1u);
    atomicAdd(&deg_d[ei[E + e]], 1u);
  }
}

__global__ __launch_bounds__(256) void k_norm(float* __restrict__ buf, int n2) {
  int i = blockIdx.x * 256 + threadIdx.x;
  if (i < n2) {
    unsigned d = ((const unsigned*)buf)[i];
    float df = (float)(d < 1u ? 1u : d);
    buf[i] = 1.0f / sqrtf(df);
  }
}

// ---------------- exclusive scan of deg_dst -> off ----------------
#define SCB 256
__global__ __launch_bounds__(SCB) void k_scan1(const unsigned* __restrict__ deg,
                                               unsigned* __restrict__ off,
                                               unsigned* __restrict__ bsum, int n) {
  __shared__ unsigned s[SCB];
  int t = threadIdx.x;
  int i = blockIdx.x * SCB + t;
  unsigned v = (i < n) ? deg[i] : 0u;
  s[t] = v;
  __syncthreads();
  #pragma unroll
  for (int o = 1; o < SCB; o <<= 1) {
    unsigned u = (t >= o) ? s[t - o] : 0u;
    __syncthreads();
    s[t] += u;
    __syncthreads();
  }
  if (i < n) off[i] = s[t] - v;
  if (t == SCB - 1) bsum[blockIdx.x] = s[t];
}

__global__ __launch_bounds__(512) void k_scan2(unsigned* __restrict__ bsum, int nb) {
  __shared__ unsigned s[512];
  int t = threadIdx.x;
  unsigned v = (t < nb) ? bsum[t] : 0u;
  s[t] = v;
  __syncthreads();
  #pragma unroll
  for (int o = 1; o < 512; o <<= 1) {
    unsigned u = (t >= o) ? s[t - o] : 0u;
    __syncthreads();
    s[t] += u;
    __syncthreads();
  }
  if (t < nb) bsum[t] = s[t] - v;
}

__global__ __launch_bounds__(SCB) void k_scan3(unsigned* __restrict__ off,
                                               const unsigned* __restrict__ bsum,
                                               int n, int E) {
  int i = blockIdx.x * SCB + threadIdx.x;
  if (i < n) off[i] += bsum[blockIdx.x];
  if (i == 0) off[n] = (unsigned)E;
}

// ---------------- CSR fill ----------------
__global__ __launch_bounds__(256) void k_fill(const int* __restrict__ ei, int E,
                                              const unsigned* __restrict__ off,
                                              unsigned* __restrict__ cursor,
                                              int* __restrict__ csr) {
  int e = blockIdx.x * 256 + threadIdx.x;
  if (e < E) {
    int s = ei[e], d = ei[E + e];
    unsigned p = atomicAdd(&cursor[d], 1u);
    csr[off[d] + p] = s;
  }
}

// ---------------- weight pre-transpose + bf16 convert ----------------
// W1t32[n][kp]: packed bf16 pair (k=2kp, 2kp+1) of W1[k][n]  (128 x 128 uints)
// W2t  [f][k] : bf16, row 47 zeroed (48 x 128 ushorts)
__global__ __launch_bounds__(256) void k_wcvt(const float* __restrict__ W1,
                                              const float* __restrict__ W2,
                                              unsigned* __restrict__ W1t32,
                                              unsigned short* __restrict__ W2t) {
  int i = blockIdx.x * 256 + threadIdx.x;
  if (i < 128 * 128) {
    int n = i >> 7, kp = i & 127;
    int k = kp << 1;
    W1t32[i] = pack2bf(W1[(size_t)k * NF1 + n], W1[(size_t)(k + 1) * NF1 + n]);
  } else if (i < 128 * 128 + 48 * 128) {
    int j = i - 128 * 128;
    int f = j >> 7, k = j & 127;
    W2t[j] = (f < NC) ? f2bf(W2[(size_t)k * NC + f]) : (unsigned short)0;
  }
}

// ---------------- GEMM1 (MFMA bf16): h1[m,n] = ns[m] * sum_k x[m,k] W1[k,n] --------
// block 256 = 4 waves; tile 128x128; K-step 32. LDS typed unsigned (bf16 pairs):
// As[row][kp] kp=0..15 (+4 pad), Bs[n][kp]. All LDS stores are uint-typed; the
// short8 MFMA fragment loads sit across __syncthreads (no TBAA reorder hazard).
__global__ __launch_bounds__(256) void k_gemm1(const float* __restrict__ x,
                                               const unsigned* __restrict__ W1t32,
                                               const float* __restrict__ norm_src,
                                               unsigned short* __restrict__ h1, int N) {
  __shared__ unsigned As[128][20];   // 16 used + 4 pad (80B row stride, 16B-aligned)
  __shared__ unsigned Bs[128][20];
  const int m0 = blockIdx.x * 128;
  const int t = threadIdx.x;
  const int lane = t & 63, wid = t >> 6;
  const int fr = lane & 15, ko = (lane >> 4) * 8;   // k-offset in bf16 units

  f32x4 acc[2][8];
  #pragma unroll
  for (int r = 0; r < 2; r++)
    #pragma unroll
    for (int c = 0; c < 8; c++) acc[r][c] = (f32x4){0.f, 0.f, 0.f, 0.f};

  const int sr = t >> 1;           // staged row 0..127
  const int shw = (t & 1) * 8;     // uint col offset: 0 or 8 (= 16 bf16)

  for (int k0 = 0; k0 < NF0; k0 += 32) {
    // stage A: x[m0+sr][k0+2*shw .. +16) fp32 -> packed bf16 pairs
    {
      unsigned w[8];
      int gm = m0 + sr;
      if (gm < N) {
        const float* p = x + (size_t)gm * NF0 + k0 + shw * 2;
        #pragma unroll
        for (int q = 0; q < 4; q++) {
          float4 v = *(const float4*)(p + q * 4);
          w[2*q]   = pack2bf(v.x, v.y);
          w[2*q+1] = pack2bf(v.z, v.w);
        }
      } else {
        #pragma unroll
        for (int q = 0; q < 8; q++) w[q] = 0u;
      }
      *(uint4*)&As[sr][shw]     = make_uint4(w[0], w[1], w[2], w[3]);
      *(uint4*)&As[sr][shw + 4] = make_uint4(w[4], w[5], w[6], w[7]);
    }
    // stage B: W1t32[sr][k0/2+shw .. +8) (already packed)
    {
      const unsigned* pb = W1t32 + (size_t)sr * (NF0 / 2) + (k0 >> 1) + shw;
      *(uint4*)&Bs[sr][shw]     = *(const uint4*)pb;
      *(uint4*)&Bs[sr][shw + 4] = *(const uint4*)(pb + 4);
    }
    __syncthreads();
    const unsigned short* As16 = (const unsigned short*)&As[0][0];
    const unsigned short* Bs16 = (const unsigned short*)&Bs[0][0];
    #pragma unroll
    for (int r = 0; r < 2; r++) {
      bfrag a = *(const bfrag*)(As16 + (size_t)(wid * 32 + r * 16 + fr) * 40 + ko);
      #pragma unroll
      for (int c = 0; c < 8; c++) {
        bfrag b = *(const bfrag*)(Bs16 + (size_t)(c * 16 + fr) * 40 + ko);
        acc[r][c] = __builtin_amdgcn_mfma_f32_16x16x32_bf16(a, b, acc[r][c], 0, 0, 0);
      }
    }
    __syncthreads();
  }

  // epilogue: D layout col=lane&15, row=(lane>>4)*4+reg (m89-verified)
  #pragma unroll
  for (int r = 0; r < 2; r++) {
    int rbase = m0 + wid * 32 + r * 16 + (lane >> 4) * 4;
    float ns[4];
    #pragma unroll
    for (int g = 0; g < 4; g++) ns[g] = (rbase + g < N) ? norm_src[rbase + g] : 0.f;
    #pragma unroll
    for (int c = 0; c < 8; c++) {
      int col = c * 16 + fr;
      #pragma unroll
      for (int g = 0; g < 4; g++) {
        int row = rbase + g;
        if (row < N) h1[(size_t)row * NF1 + col] = f2bf(acc[r][c][g] * ns[g]);
      }
    }
  }
}

// ---------------- gather1: h2 = bf16(dropout(relu(nd*sum h1[src] + b1)) * ns) ------
__global__ __launch_bounds__(256) void k_gather1(const unsigned* __restrict__ off,
                                                 const int* __restrict__ csr,
                                                 const unsigned short* __restrict__ h1,
                                                 const float* __restrict__ norm_dst,
                                                 const float* __restrict__ norm_src,
                                                 const float* __restrict__ b1,
                                                 unsigned short* __restrict__ h2, int N) {
  int node = (blockIdx.x * 256 + threadIdx.x) >> 6;
  int lane = threadIdx.x & 63;
  if (node >= N) return;
  unsigned j = off[node], e1 = off[node + 1];
  int f = lane << 1;
  float ax = 0.f, ay = 0.f;
  for (; j + 4 <= e1; j += 4) {
    int s0 = csr[j], s1 = csr[j+1], s2 = csr[j+2], s3 = csr[j+3];
    unsigned v0 = *(const unsigned*)(h1 + (size_t)s0 * NF1 + f);
    unsigned v1 = *(const unsigned*)(h1 + (size_t)s1 * NF1 + f);
    unsigned v2 = *(const unsigned*)(h1 + (size_t)s2 * NF1 + f);
    unsigned v3 = *(const unsigned*)(h1 + (size_t)s3 * NF1 + f);
    ax += (bflo(v0) + bflo(v1)) + (bflo(v2) + bflo(v3));
    ay += (bfhi(v0) + bfhi(v1)) + (bfhi(v2) + bfhi(v3));
  }
  for (; j < e1; j++) {
    unsigned v = *(const unsigned*)(h1 + (size_t)csr[j] * NF1 + f);
    ax += bflo(v); ay += bfhi(v);
  }
  float nd = norm_dst[node], ns = norm_src[node];
  float2 bb = *(const float2*)(b1 + f);
  float v0 = fmaxf(ax * nd + bb.x, 0.f);
  float v1 = fmaxf(ay * nd + bb.y, 0.f);
  int jf = node * NF1 + f;
  v0 *= dropout_mul(jf) * ns;
  v1 *= dropout_mul(jf + 1) * ns;
  *(unsigned*)(h2 + (size_t)node * NF1 + f) = pack2bf(v0, v1);
}

// ---------------- GEMM2: g[m,f] = sum_k h2[m,k] W2[k,f]; bf16 in/out, fp32 math ----
__global__ __launch_bounds__(256) void k_gemm2(const unsigned short* __restrict__ h2,
                                               const unsigned short* __restrict__ W2t,
                                               unsigned short* __restrict__ g, int N) {
  __shared__ float hs[64][132];
  __shared__ float w2t[48][132];
  const int m0 = blockIdx.x * 64;
  const int t = threadIdx.x;
  #pragma unroll
  for (int l = t; l < 64 * 16; l += 256) {      // 8 bf16 per iter
    int r = l >> 4, c8 = (l & 15) << 3;
    int gm = m0 + r;
    float f[8];
    if (gm < N) {
      uint4 v = *(const uint4*)(h2 + (size_t)gm * NF1 + c8);
      f[0]=bflo(v.x); f[1]=bfhi(v.x); f[2]=bflo(v.y); f[3]=bfhi(v.y);
      f[4]=bflo(v.z); f[5]=bfhi(v.z); f[6]=bflo(v.w); f[7]=bfhi(v.w);
    } else {
      #pragma unroll
      for (int q = 0; q < 8; q++) f[q] = 0.f;
    }
    *(float4*)&hs[r][c8]     = make_float4(f[0], f[1], f[2], f[3]);
    *(float4*)&hs[r][c8 + 4] = make_float4(f[4], f[5], f[6], f[7]);
  }
  for (int l = t; l < 48 * 128; l += 256) {
    int n = l >> 7, k = l & 127;
    w2t[n][k] = bf2f(W2t[l]);
  }
  __syncthreads();
  const int fg = t & 15, mg = t >> 4;
  const int f0 = fg * 3, mt = mg * 4;
  float acc[4][3] = {{0.f}};
  for (int k = 0; k < NF1; k += 4) {
    float4 a[4], b[3];
    #pragma unroll
    for (int i = 0; i < 4; i++) a[i] = *(float4*)&hs[mt + i][k];
    #pragma unroll
    for (int j = 0; j < 3; j++) b[j] = *(float4*)&w2t[f0 + j][k];
    #pragma unroll
    for (int i = 0; i < 4; i++)
      #pragma unroll
      for (int j = 0; j < 3; j++)
        acc[i][j] += a[i].x*b[j].x + a[i].y*b[j].y + a[i].z*b[j].z + a[i].w*b[j].w;
  }
  #pragma unroll
  for (int i = 0; i < 4; i++) {
    int gm = m0 + mt + i;
    if (gm < N) {
      #pragma unroll
      for (int j = 0; j < 3; j++)
        g[(size_t)gm * 48 + f0 + j] = f2bf(acc[i][j]);
    }
  }
}

// ---------------- gather2 + bias + log_softmax -> out ----------------
__global__ __launch_bounds__(256) void k_gather2(const unsigned* __restrict__ off,
                                                 const int* __restrict__ csr,
                                                 const unsigned short* __restrict__ g,
                                                 const float* __restrict__ norm_dst,
                                                 const float* __restrict__ b2,
                                                 float* __restrict__ out, int N) {
  int node = (blockIdx.x * 256 + threadIdx.x) >> 6;
  int lane = threadIdx.x & 63;
  if (node >= N) return;
  unsigned j = off[node], e1 = off[node + 1];
  float acc = 0.f;
  for (; j + 4 <= e1; j += 4) {
    int s0 = csr[j], s1 = csr[j+1], s2 = csr[j+2], s3 = csr[j+3];
    if (lane < 48) {
      float a0 = bf2f(g[(size_t)s0 * 48 + lane]);
      float a1 = bf2f(g[(size_t)s1 * 48 + lane]);
      float a2 = bf2f(g[(size_t)s2 * 48 + lane]);
      float a3 = bf2f(g[(size_t)s3 * 48 + lane]);
      acc += (a0 + a1) + (a2 + a3);
    }
  }
  for (; j < e1; j++) {
    if (lane < 48) acc += bf2f(g[(size_t)csr[j] * 48 + lane]);
  }
  float nd = norm_dst[node];
  float vr = 0.f, m = -INFINITY;
  if (lane < NC) {
    vr = acc * nd + b2[lane];
    m = vr;
  }
  #pragma unroll
  for (int o = 32; o; o >>= 1) m = fmaxf(m, __shfl_xor(m, o));
  float ex = (lane < NC) ? expf(vr - m) : 0.f;
  #pragma unroll
  for (int o = 32; o; o >>= 1) ex += __shfl_xor(ex, o);
  float ls = logf(ex);
  if (lane < NC) out[(size_t)node * NC + lane] = vr - m - ls;
}

extern "C" void kernel_launch(void* const* d_in, const int* in_sizes, int n_in,
                              void* d_out, int out_size, void* d_ws, size_t ws_size,
                              hipStream_t stream) {
  const float* x  = (const float*)d_in[0];
  const int*   ei = (const int*)d_in[1];
  const float* W1 = (const float*)d_in[2];
  const float* b1 = (const float*)d_in[3];
  const float* W2 = (const float*)d_in[4];
  const float* b2 = (const float*)d_in[5];
  float* out = (float*)d_out;

  const int N = in_sizes[0] / NF0;   // 100000
  const int E = in_sizes[1] / 2;     // 1600000
  const int nb = (N + SCB - 1) / SCB;

  unsigned* ws = (unsigned*)d_ws;
  size_t o = 0;
  auto alloc = [&](size_t elems) { size_t p = o; o += (elems + 3) & ~(size_t)3; return p; };
  unsigned* deg_src = ws + alloc(N);
  unsigned* deg_dst = ws + alloc(N);
  unsigned* cursor  = ws + alloc(N);
  unsigned* off     = ws + alloc(N + 1);
  unsigned* bsum    = ws + alloc(1024);
  int*      csr     = (int*)(ws + alloc(E));
  unsigned* W1t32   = ws + alloc(128 * 128);
  unsigned short* W2t = (unsigned short*)(ws + alloc(48 * 128 / 2));
  unsigned short* h1  = (unsigned short*)(ws + alloc((size_t)N * NF1 / 2));
  size_t need_h2 = (o + (size_t)N * NF1 / 2) * 4;
  unsigned short* h2 = (ws_size >= need_h2)
                           ? (unsigned short*)(ws + alloc((size_t)N * NF1 / 2))
                           : (unsigned short*)d_in[0];  // overlay x (dead after gemm1)
  unsigned short* g = h1;   // h1 dead after gather1; g needs N*48*2 < N*128*2

  hipMemsetAsync(deg_src, 0, (size_t)3 * N * sizeof(unsigned), stream);

  k_degree<<<(E + 255) / 256, 256, 0, stream>>>(ei, E, deg_src, deg_dst);
  k_scan1<<<nb, SCB, 0, stream>>>(deg_dst, off, bsum, N);
  k_scan2<<<1, 512, 0, stream>>>(bsum, nb);
  k_scan3<<<nb, SCB, 0, stream>>>(off, bsum, N, E);
  k_norm<<<(2 * N + 255) / 256, 256, 0, stream>>>((float*)deg_src, 2 * N);
  k_fill<<<(E + 255) / 256, 256, 0, stream>>>(ei, E, off, cursor, csr);
  k_wcvt<<<(128 * 128 + 48 * 128 + 255) / 256, 256, 0, stream>>>(W1, W2, W1t32, W2t);
  k_gemm1<<<(N + 127) / 128, 256, 0, stream>>>(x, W1t32, (const float*)deg_src, h1, N);
  k_gather1<<<((size_t)N * 64 + 255) / 256, 256, 0, stream>>>(
      off, csr, h1, (const float*)deg_dst, (const float*)deg_src, b1, h2, N);
  k_gemm2<<<(N + 63) / 64, 256, 0, stream>>>(h2, W2t, g, N);
  k_gather2<<<((size_t)N * 64 + 255) / 256, 256, 0, stream>>>(
      off, csr, g, (const float*)deg_dst, b2, out, N);
}

// Round 5
// 513.166 us; speedup vs baseline: 6.8854x; 1.2381x over previous
//
#include <hip/hip_runtime.h>
#include <math.h>

// GCN 2-layer forward, MI355X. Round 5: atomic-free CSR build (2-level bucket
// sort; LDS histograms + chunk reservation) replacing k_degree/k_fill/scans.
// Downstream pipeline (MFMA gemm1, bf16 gathers, gemm2) unchanged from r4.
// Assumes N <= 131072 (src packed in 17 bits; N=100000 here).

#define NF0 256
#define NF1 128
#define NC  47
#define CB  1024   // fine bucket width (nodes per coarse bucket)

typedef __attribute__((ext_vector_type(8))) short bfrag;   // 8 bf16 (4 VGPRs)
typedef __attribute__((ext_vector_type(4))) float f32x4;

__device__ __forceinline__ unsigned short f2bf(float f) {   // RNE
  unsigned u = __float_as_uint(f);
  return (unsigned short)((u + 0x7fffu + ((u >> 16) & 1u)) >> 16);
}
__device__ __forceinline__ unsigned pack2bf(float a, float b) {
  return (unsigned)f2bf(a) | ((unsigned)f2bf(b) << 16);
}
__device__ __forceinline__ float bf2f(unsigned short b) {
  return __uint_as_float((unsigned)b << 16);
}
__device__ __forceinline__ float bflo(unsigned v) { return __uint_as_float(v << 16); }
__device__ __forceinline__ float bfhi(unsigned v) { return __uint_as_float(v & 0xffff0000u); }

// ---------------- threefry2x32 (JAX partitionable path; verified r1/r2) ------------
__device__ __forceinline__ unsigned rotl_(unsigned x, int n) {
  return (x << n) | (x >> (32 - n));
}
__device__ __forceinline__ void threefry2x32_(unsigned x0, unsigned x1,
                                              unsigned& o0, unsigned& o1) {
  const unsigned k0 = 0u, k1 = 42u;
  const unsigned k2 = k0 ^ k1 ^ 0x1BD11BDAu;
  x0 += k0; x1 += k1;
  x0+=x1; x1=rotl_(x1,13); x1^=x0;
  x0+=x1; x1=rotl_(x1,15); x1^=x0;
  x0+=x1; x1=rotl_(x1,26); x1^=x0;
  x0+=x1; x1=rotl_(x1, 6); x1^=x0;
  x0+=k1; x1+=k2+1u;
  x0+=x1; x1=rotl_(x1,17); x1^=x0;
  x0+=x1; x1=rotl_(x1,29); x1^=x0;
  x0+=x1; x1=rotl_(x1,16); x1^=x0;
  x0+=x1; x1=rotl_(x1,24); x1^=x0;
  x0+=k2; x1+=k0+2u;
  x0+=x1; x1=rotl_(x1,13); x1^=x0;
  x0+=x1; x1=rotl_(x1,15); x1^=x0;
  x0+=x1; x1=rotl_(x1,26); x1^=x0;
  x0+=x1; x1=rotl_(x1, 6); x1^=x0;
  x0+=k0; x1+=k1+3u;
  x0+=x1; x1=rotl_(x1,17); x1^=x0;
  x0+=x1; x1=rotl_(x1,29); x1^=x0;
  x0+=x1; x1=rotl_(x1,16); x1^=x0;
  x0+=x1; x1=rotl_(x1,24); x1^=x0;
  x0+=k1; x1+=k2+4u;
  x0+=x1; x1=rotl_(x1,13); x1^=x0;
  x0+=x1; x1=rotl_(x1,15); x1^=x0;
  x0+=x1; x1=rotl_(x1,26); x1^=x0;
  x0+=x1; x1=rotl_(x1, 6); x1^=x0;
  x0+=k2; x1+=k0+5u;
  o0 = x0; o1 = x1;
}
__device__ __forceinline__ float dropout_mul(int j) {
  unsigned o0, o1;
  threefry2x32_(0u, (unsigned)j, o0, o1);
  unsigned bits = o0 ^ o1;
  float u = __uint_as_float((bits >> 9) | 0x3f800000u) - 1.0f;
  return (u < 0.8f) ? 1.25f : 0.0f;
}

// ================= atomic-free CSR build =================

// P1: coarse histogram of src and dst into nbk (<128) buckets of CB nodes.
__global__ __launch_bounds__(256) void k_chist(const int* __restrict__ ei, int E,
                                               int nbk,
                                               unsigned* __restrict__ bCntD,
                                               unsigned* __restrict__ bCntS) {
  __shared__ unsigned hd[128], hs[128];
  for (int i = threadIdx.x; i < 128; i += 256) { hd[i] = 0; hs[i] = 0; }
  __syncthreads();
  for (int e = blockIdx.x * 256 + threadIdx.x; e < E; e += gridDim.x * 256) {
    int s = ei[e], d = ei[E + e];
    atomicAdd(&hs[s >> 10], 1u);
    atomicAdd(&hd[d >> 10], 1u);
  }
  __syncthreads();
  for (int i = threadIdx.x; i < nbk; i += 256) {
    if (hd[i]) atomicAdd(&bCntD[i], hd[i]);
    if (hs[i]) atomicAdd(&bCntS[i], hs[i]);
  }
}

// P2: tiny scan of coarse counts; init cursors; off[N]=E.
__global__ void k_cscan(const unsigned* __restrict__ bCntD,
                        const unsigned* __restrict__ bCntS,
                        unsigned* __restrict__ bOffD, unsigned* __restrict__ bOffS,
                        unsigned* __restrict__ curD, unsigned* __restrict__ curS,
                        unsigned* __restrict__ off, int nbk, int N, int E) {
  if (threadIdx.x == 0) {
    unsigned a = 0, b = 0;
    for (int i = 0; i < nbk; i++) {
      bOffD[i] = a; curD[i] = a; a += bCntD[i];
      bOffS[i] = b; curS[i] = b; b += bCntS[i];
    }
    bOffD[nbk] = a; bOffS[nbk] = b;
    off[N] = (unsigned)E;
  }
}

// P3: scatter edges to coarse buckets. Per block: LDS hist of its slice,
// one chunk-reservation atomic per bucket (not per edge), then LDS-cursor
// sequential placement. pd = (dstLocal<<17)|src keyed by dst; ps = srcLocal.
__global__ __launch_bounds__(256) void k_cscatter(const int* __restrict__ ei, int E,
                                                  unsigned* __restrict__ curD,
                                                  unsigned* __restrict__ curS,
                                                  unsigned* __restrict__ pd,
                                                  unsigned short* __restrict__ ps) {
  __shared__ unsigned hd[128], hs[128];
  __shared__ unsigned baseD[128], baseS[128];
  int per = (E + gridDim.x - 1) / gridDim.x;
  int e0 = blockIdx.x * per;
  int e1 = min(e0 + per, E);
  for (int i = threadIdx.x; i < 128; i += 256) { hd[i] = 0; hs[i] = 0; }
  __syncthreads();
  for (int e = e0 + threadIdx.x; e < e1; e += 256) {
    int s = ei[e], d = ei[E + e];
    atomicAdd(&hs[s >> 10], 1u);
    atomicAdd(&hd[d >> 10], 1u);
  }
  __syncthreads();
  for (int i = threadIdx.x; i < 128; i += 256) {
    baseD[i] = hd[i] ? atomicAdd(&curD[i], hd[i]) : 0u;
    baseS[i] = hs[i] ? atomicAdd(&curS[i], hs[i]) : 0u;
    hd[i] = 0; hs[i] = 0;            // reuse as local cursors
  }
  __syncthreads();
  for (int e = e0 + threadIdx.x; e < e1; e += 256) {
    int s = ei[e], d = ei[E + e];
    int bd = d >> 10, bs = s >> 10;
    unsigned pD = baseD[bd] + atomicAdd(&hd[bd], 1u);
    unsigned pS = baseS[bs] + atomicAdd(&hs[bs], 1u);
    pd[pD] = ((unsigned)(d & (CB - 1)) << 17) | (unsigned)s;
    ps[pS] = (unsigned short)(s & (CB - 1));
  }
}

// P4: per dst-bucket fine CSR: LDS count(1024) -> LDS scan -> write deg_dst,
// off (coalesced) -> LDS-cursor scatter of src into csr. Zero global atomics.
__global__ __launch_bounds__(256) void k_fcsr(const unsigned* __restrict__ bOffD,
                                              const unsigned* __restrict__ pd,
                                              unsigned* __restrict__ off,
                                              unsigned* __restrict__ deg_dst, int N,
                                              int* __restrict__ csr) {
  __shared__ unsigned cnt[CB];
  __shared__ unsigned part[256];
  const int b = blockIdx.x, t = threadIdx.x;
  const unsigned lo = bOffD[b], hi = bOffD[b + 1];
  const int base = b << 10;
  for (int i = t; i < CB; i += 256) cnt[i] = 0;
  __syncthreads();
  for (unsigned j = lo + t; j < hi; j += 256) atomicAdd(&cnt[pd[j] >> 17], 1u);
  __syncthreads();
  unsigned c0 = cnt[4*t], c1 = cnt[4*t+1], c2 = cnt[4*t+2], c3 = cnt[4*t+3];
  unsigned tsum = c0 + c1 + c2 + c3;
  part[t] = tsum;
  __syncthreads();
  #pragma unroll
  for (int o = 1; o < 256; o <<= 1) {
    unsigned u = (t >= o) ? part[t - o] : 0u;
    __syncthreads();
    part[t] += u;
    __syncthreads();
  }
  unsigned e0 = part[t] - tsum;           // exclusive base for this thread's 4
  unsigned p0 = e0, p1 = e0 + c0, p2 = p1 + c1, p3 = p2 + c2;
  int n0 = base + 4 * t;
  if (n0 + 0 < N) { off[n0 + 0] = lo + p0; deg_dst[n0 + 0] = c0; }
  if (n0 + 1 < N) { off[n0 + 1] = lo + p1; deg_dst[n0 + 1] = c1; }
  if (n0 + 2 < N) { off[n0 + 2] = lo + p2; deg_dst[n0 + 2] = c2; }
  if (n0 + 3 < N) { off[n0 + 3] = lo + p3; deg_dst[n0 + 3] = c3; }
  __syncthreads();
  cnt[4*t] = p0; cnt[4*t+1] = p1; cnt[4*t+2] = p2; cnt[4*t+3] = p3;  // cursors
  __syncthreads();
  for (unsigned j = lo + t; j < hi; j += 256) {
    unsigned v = pd[j];
    unsigned pos = atomicAdd(&cnt[v >> 17], 1u);
    csr[lo + pos] = (int)(v & 0x1FFFFu);
  }
}

// P5: per src-bucket fine histogram -> deg_src.
__global__ __launch_bounds__(256) void k_fhist(const unsigned* __restrict__ bOffS,
                                               const unsigned short* __restrict__ ps,
                                               unsigned* __restrict__ deg_src, int N) {
  __shared__ unsigned cnt[CB];
  const int b = blockIdx.x, t = threadIdx.x;
  const unsigned lo = bOffS[b], hi = bOffS[b + 1];
  const int base = b << 10;
  for (int i = t; i < CB; i += 256) cnt[i] = 0;
  __syncthreads();
  for (unsigned j = lo + t; j < hi; j += 256) atomicAdd(&cnt[ps[j]], 1u);
  __syncthreads();
  for (int i = t; i < CB; i += 256)
    if (base + i < N) deg_src[base + i] = cnt[i];
}

// ---------------- norms ----------------
__global__ __launch_bounds__(256) void k_norm(float* __restrict__ buf, int n2) {
  int i = blockIdx.x * 256 + threadIdx.x;
  if (i < n2) {
    unsigned d = ((const unsigned*)buf)[i];
    float df = (float)(d < 1u ? 1u : d);
    buf[i] = 1.0f / sqrtf(df);
  }
}

// ---------------- weight pre-transpose + bf16 convert ----------------
__global__ __launch_bounds__(256) void k_wcvt(const float* __restrict__ W1,
                                              const float* __restrict__ W2,
                                              unsigned* __restrict__ W1t32,
                                              unsigned short* __restrict__ W2t) {
  int i = blockIdx.x * 256 + threadIdx.x;
  if (i < 128 * 128) {
    int n = i >> 7, kp = i & 127;
    int k = kp << 1;
    W1t32[i] = pack2bf(W1[(size_t)k * NF1 + n], W1[(size_t)(k + 1) * NF1 + n]);
  } else if (i < 128 * 128 + 48 * 128) {
    int j = i - 128 * 128;
    int f = j >> 7, k = j & 127;
    W2t[j] = (f < NC) ? f2bf(W2[(size_t)k * NC + f]) : (unsigned short)0;
  }
}

// ---------------- GEMM1 (MFMA bf16): h1[m,n] = ns[m] * sum_k x[m,k] W1[k,n] --------
__global__ __launch_bounds__(256) void k_gemm1(const float* __restrict__ x,
                                               const unsigned* __restrict__ W1t32,
                                               const float* __restrict__ norm_src,
                                               unsigned short* __restrict__ h1, int N) {
  __shared__ unsigned As[128][20];   // 16 used + 4 pad
  __shared__ unsigned Bs[128][20];
  const int m0 = blockIdx.x * 128;
  const int t = threadIdx.x;
  const int lane = t & 63, wid = t >> 6;
  const int fr = lane & 15, ko = (lane >> 4) * 8;

  f32x4 acc[2][8];
  #pragma unroll
  for (int r = 0; r < 2; r++)
    #pragma unroll
    for (int c = 0; c < 8; c++) acc[r][c] = (f32x4){0.f, 0.f, 0.f, 0.f};

  const int sr = t >> 1;
  const int shw = (t & 1) * 8;

  for (int k0 = 0; k0 < NF0; k0 += 32) {
    {
      unsigned w[8];
      int gm = m0 + sr;
      if (gm < N) {
        const float* p = x + (size_t)gm * NF0 + k0 + shw * 2;
        #pragma unroll
        for (int q = 0; q < 4; q++) {
          float4 v = *(const float4*)(p + q * 4);
          w[2*q]   = pack2bf(v.x, v.y);
          w[2*q+1] = pack2bf(v.z, v.w);
        }
      } else {
        #pragma unroll
        for (int q = 0; q < 8; q++) w[q] = 0u;
      }
      *(uint4*)&As[sr][shw]     = make_uint4(w[0], w[1], w[2], w[3]);
      *(uint4*)&As[sr][shw + 4] = make_uint4(w[4], w[5], w[6], w[7]);
    }
    {
      const unsigned* pb = W1t32 + (size_t)sr * (NF0 / 2) + (k0 >> 1) + shw;
      *(uint4*)&Bs[sr][shw]     = *(const uint4*)pb;
      *(uint4*)&Bs[sr][shw + 4] = *(const uint4*)(pb + 4);
    }
    __syncthreads();
    const unsigned short* As16 = (const unsigned short*)&As[0][0];
    const unsigned short* Bs16 = (const unsigned short*)&Bs[0][0];
    #pragma unroll
    for (int r = 0; r < 2; r++) {
      bfrag a = *(const bfrag*)(As16 + (size_t)(wid * 32 + r * 16 + fr) * 40 + ko);
      #pragma unroll
      for (int c = 0; c < 8; c++) {
        bfrag b = *(const bfrag*)(Bs16 + (size_t)(c * 16 + fr) * 40 + ko);
        acc[r][c] = __builtin_amdgcn_mfma_f32_16x16x32_bf16(a, b, acc[r][c], 0, 0, 0);
      }
    }
    __syncthreads();
  }

  #pragma unroll
  for (int r = 0; r < 2; r++) {
    int rbase = m0 + wid * 32 + r * 16 + (lane >> 4) * 4;
    float ns[4];
    #pragma unroll
    for (int g = 0; g < 4; g++) ns[g] = (rbase + g < N) ? norm_src[rbase + g] : 0.f;
    #pragma unroll
    for (int c = 0; c < 8; c++) {
      int col = c * 16 + fr;
      #pragma unroll
      for (int g = 0; g < 4; g++) {
        int row = rbase + g;
        if (row < N) h1[(size_t)row * NF1 + col] = f2bf(acc[r][c][g] * ns[g]);
      }
    }
  }
}

// ---------------- gather1: h2 = bf16(dropout(relu(nd*sum h1[src] + b1)) * ns) ------
__global__ __launch_bounds__(256) void k_gather1(const unsigned* __restrict__ off,
                                                 const int* __restrict__ csr,
                                                 const unsigned short* __restrict__ h1,
                                                 const float* __restrict__ norm_dst,
                                                 const float* __restrict__ norm_src,
                                                 const float* __restrict__ b1,
                                                 unsigned short* __restrict__ h2, int N) {
  int node = (blockIdx.x * 256 + threadIdx.x) >> 6;
  int lane = threadIdx.x & 63;
  if (node >= N) return;
  unsigned j = off[node], e1 = off[node + 1];
  int f = lane << 1;
  float ax = 0.f, ay = 0.f;
  for (; j + 4 <= e1; j += 4) {
    int s0 = csr[j], s1 = csr[j+1], s2 = csr[j+2], s3 = csr[j+3];
    unsigned v0 = *(const unsigned*)(h1 + (size_t)s0 * NF1 + f);
    unsigned v1 = *(const unsigned*)(h1 + (size_t)s1 * NF1 + f);
    unsigned v2 = *(const unsigned*)(h1 + (size_t)s2 * NF1 + f);
    unsigned v3 = *(const unsigned*)(h1 + (size_t)s3 * NF1 + f);
    ax += (bflo(v0) + bflo(v1)) + (bflo(v2) + bflo(v3));
    ay += (bfhi(v0) + bfhi(v1)) + (bfhi(v2) + bfhi(v3));
  }
  for (; j < e1; j++) {
    unsigned v = *(const unsigned*)(h1 + (size_t)csr[j] * NF1 + f);
    ax += bflo(v); ay += bfhi(v);
  }
  float nd = norm_dst[node], ns = norm_src[node];
  float2 bb = *(const float2*)(b1 + f);
  float v0 = fmaxf(ax * nd + bb.x, 0.f);
  float v1 = fmaxf(ay * nd + bb.y, 0.f);
  int jf = node * NF1 + f;
  v0 *= dropout_mul(jf) * ns;
  v1 *= dropout_mul(jf + 1) * ns;
  *(unsigned*)(h2 + (size_t)node * NF1 + f) = pack2bf(v0, v1);
}

// ---------------- GEMM2: g[m,f] = sum_k h2[m,k] W2[k,f]; bf16 in/out, fp32 math ----
__global__ __launch_bounds__(256) void k_gemm2(const unsigned short* __restrict__ h2,
                                               const unsigned short* __restrict__ W2t,
                                               unsigned short* __restrict__ g, int N) {
  __shared__ float hs[64][132];
  __shared__ float w2t[48][132];
  const int m0 = blockIdx.x * 64;
  const int t = threadIdx.x;
  #pragma unroll
  for (int l = t; l < 64 * 16; l += 256) {
    int r = l >> 4, c8 = (l & 15) << 3;
    int gm = m0 + r;
    float f[8];
    if (gm < N) {
      uint4 v = *(const uint4*)(h2 + (size_t)gm * NF1 + c8);
      f[0]=bflo(v.x); f[1]=bfhi(v.x); f[2]=bflo(v.y); f[3]=bfhi(v.y);
      f[4]=bflo(v.z); f[5]=bfhi(v.z); f[6]=bflo(v.w); f[7]=bfhi(v.w);
    } else {
      #pragma unroll
      for (int q = 0; q < 8; q++) f[q] = 0.f;
    }
    *(float4*)&hs[r][c8]     = make_float4(f[0], f[1], f[2], f[3]);
    *(float4*)&hs[r][c8 + 4] = make_float4(f[4], f[5], f[6], f[7]);
  }
  for (int l = t; l < 48 * 128; l += 256) {
    int n = l >> 7, k = l & 127;
    w2t[n][k] = bf2f(W2t[l]);
  }
  __syncthreads();
  const int fg = t & 15, mg = t >> 4;
  const int f0 = fg * 3, mt = mg * 4;
  float acc[4][3] = {{0.f}};
  for (int k = 0; k < NF1; k += 4) {
    float4 a[4], b[3];
    #pragma unroll
    for (int i = 0; i < 4; i++) a[i] = *(float4*)&hs[mt + i][k];
    #pragma unroll
    for (int j = 0; j < 3; j++) b[j] = *(float4*)&w2t[f0 + j][k];
    #pragma unroll
    for (int i = 0; i < 4; i++)
      #pragma unroll
      for (int j = 0; j < 3; j++)
        acc[i][j] += a[i].x*b[j].x + a[i].y*b[j].y + a[i].z*b[j].z + a[i].w*b[j].w;
  }
  #pragma unroll
  for (int i = 0; i < 4; i++) {
    int gm = m0 + mt + i;
    if (gm < N) {
      #pragma unroll
      for (int j = 0; j < 3; j++)
        g[(size_t)gm * 48 + f0 + j] = f2bf(acc[i][j]);
    }
  }
}

// ---------------- gather2 + bias + log_softmax -> out ----------------
__global__ __launch_bounds__(256) void k_gather2(const unsigned* __restrict__ off,
                                                 const int* __restrict__ csr,
                                                 const unsigned short* __restrict__ g,
                                                 const float* __restrict__ norm_dst,
                                                 const float* __restrict__ b2,
                                                 float* __restrict__ out, int N) {
  int node = (blockIdx.x * 256 + threadIdx.x) >> 6;
  int lane = threadIdx.x & 63;
  if (node >= N) return;
  unsigned j = off[node], e1 = off[node + 1];
  float acc = 0.f;
  for (; j + 4 <= e1; j += 4) {
    int s0 = csr[j], s1 = csr[j+1], s2 = csr[j+2], s3 = csr[j+3];
    if (lane < 48) {
      float a0 = bf2f(g[(size_t)s0 * 48 + lane]);
      float a1 = bf2f(g[(size_t)s1 * 48 + lane]);
      float a2 = bf2f(g[(size_t)s2 * 48 + lane]);
      float a3 = bf2f(g[(size_t)s3 * 48 + lane]);
      acc += (a0 + a1) + (a2 + a3);
    }
  }
  for (; j < e1; j++) {
    if (lane < 48) acc += bf2f(g[(size_t)csr[j] * 48 + lane]);
  }
  float nd = norm_dst[node];
  float vr = 0.f, m = -INFINITY;
  if (lane < NC) {
    vr = acc * nd + b2[lane];
    m = vr;
  }
  #pragma unroll
  for (int o = 32; o; o >>= 1) m = fmaxf(m, __shfl_xor(m, o));
  float ex = (lane < NC) ? expf(vr - m) : 0.f;
  #pragma unroll
  for (int o = 32; o; o >>= 1) ex += __shfl_xor(ex, o);
  float ls = logf(ex);
  if (lane < NC) out[(size_t)node * NC + lane] = vr - m - ls;
}

extern "C" void kernel_launch(void* const* d_in, const int* in_sizes, int n_in,
                              void* d_out, int out_size, void* d_ws, size_t ws_size,
                              hipStream_t stream) {
  const float* x  = (const float*)d_in[0];
  const int*   ei = (const int*)d_in[1];
  const float* W1 = (const float*)d_in[2];
  const float* b1 = (const float*)d_in[3];
  const float* W2 = (const float*)d_in[4];
  const float* b2 = (const float*)d_in[5];
  float* out = (float*)d_out;

  const int N = in_sizes[0] / NF0;   // 100000
  const int E = in_sizes[1] / 2;     // 1600000
  const int nbk = (N + CB - 1) / CB; // 98

  unsigned* ws = (unsigned*)d_ws;
  size_t o = 0;
  auto alloc = [&](size_t elems) { size_t p = o; o += (elems + 3) & ~(size_t)3; return p; };
  unsigned* deg_src = ws + alloc(N);        // adjacent to deg_dst (N % 4 == 0)
  unsigned* deg_dst = ws + alloc(N);
  unsigned* off     = ws + alloc(N + 1);
  unsigned* bCntD   = ws + alloc(128);      // adjacent to bCntS for one memset
  unsigned* bCntS   = ws + alloc(128);
  unsigned* bOffD   = ws + alloc(132);
  unsigned* bOffS   = ws + alloc(132);
  unsigned* curD    = ws + alloc(128);
  unsigned* curS    = ws + alloc(128);
  unsigned* pd      = ws + alloc(E);                       // 6.4 MB
  unsigned short* ps = (unsigned short*)(ws + alloc(E / 2)); // 3.2 MB
  int*      csr     = (int*)(ws + alloc(E));               // 6.4 MB
  unsigned* W1t32   = ws + alloc(128 * 128);
  unsigned short* W2t = (unsigned short*)(ws + alloc(48 * 128 / 2));
  unsigned short* h1  = (unsigned short*)(ws + alloc((size_t)N * NF1 / 2));
  size_t need_h2 = (o + (size_t)N * NF1 / 2) * 4;
  unsigned short* h2 = (ws_size >= need_h2)
                           ? (unsigned short*)(ws + alloc((size_t)N * NF1 / 2))
                           : (unsigned short*)d_in[0];  // overlay x (dead after gemm1)
  unsigned short* g = h1;   // h1 dead after gather1

  hipMemsetAsync(bCntD, 0, 256 * sizeof(unsigned), stream);

  k_chist<<<256, 256, 0, stream>>>(ei, E, nbk, bCntD, bCntS);
  k_cscan<<<1, 64, 0, stream>>>(bCntD, bCntS, bOffD, bOffS, curD, curS, off, nbk, N, E);
  k_cscatter<<<256, 256, 0, stream>>>(ei, E, curD, curS, pd, ps);
  k_fcsr<<<nbk, 256, 0, stream>>>(bOffD, pd, off, deg_dst, N, csr);
  k_fhist<<<nbk, 256, 0, stream>>>(bOffS, ps, deg_src, N);
  k_norm<<<(2 * N + 255) / 256, 256, 0, stream>>>((float*)deg_src, 2 * N);
  k_wcvt<<<(128 * 128 + 48 * 128 + 255) / 256, 256, 0, stream>>>(W1, W2, W1t32, W2t);
  k_gemm1<<<(N + 127) / 128, 256, 0, stream>>>(x, W1t32, (const float*)deg_src, h1, N);
  k_gather1<<<((size_t)N * 64 + 255) / 256, 256, 0, stream>>>(
      off, csr, h1, (const float*)deg_dst, (const float*)deg_src, b1, h2, N);
  k_gemm2<<<(N + 63) / 64, 256, 0, stream>>>(h2, W2t, g, N);
  k_gather2<<<((size_t)N * 64 + 255) / 256, 256, 0, stream>>>(
      off, csr, g, (const float*)deg_dst, b2, out, N);
}